// Round 5
// baseline (264.332 us; speedup 1.0000x reference)
//
#include <hip/hip_runtime.h>

// 2-layer GCN, CSR-gather formulation, v5.
//   Â = D^{-1/2}(A+I)D^{-1/2},  out = Â(relu(Â z W1 + b1))W2 + b2
// layer1: t1 = Â z (64-wide), h = relu(t1@W1+b1); layer2: hh = h@W2, out = Â hh + b2.
// v5: degree/rank atomics use 4 REPLICated counters per node (contention /4);
// merge kernel folds replicas -> counts, dinv, per-replica base offsets, so the
// CSR scatter stays atomic-free. degpack: 4 atomics in flight per thread.
// gagg: 16 edges in flight per wave (4 subgroups x 4-deep unroll).

__device__ __forceinline__ float4 ld4(const float* p) {
    return *reinterpret_cast<const float4*>(p);
}

// ---------------- pass A: replicated packed degree/count + per-edge local rank ----
// packed4[d*4+r]: bits 20..31 = count, bits 0..19 = sum(ew) in 2^-14 fixed point.
__global__ __launch_bounds__(256) void degpack_kernel(const int* __restrict__ dst,
                                                      const float* __restrict__ ew,
                                                      unsigned int* __restrict__ packed4,
                                                      unsigned short* __restrict__ rank,
                                                      int E) {
    int base = blockIdx.x * 1024 + (int)threadIdx.x;
#pragma unroll
    for (int k = 0; k < 4; ++k) {
        int e = base + k * 256;
        if (e < E) {
            int d = dst[e];
            unsigned int add = (1u << 20) | (unsigned int)(ew[e] * 16384.0f);
            unsigned int old = atomicAdd(&packed4[(size_t)d * 4 + (e & 3)], add);
            rank[e] = (unsigned short)(old >> 20);
        }
    }
}

// merge replicas: counts[i], dinv[i], base4[i] (prefix of replica counts)
__global__ __launch_bounds__(256) void merge_kernel(const uint4* __restrict__ packed4,
                                                    float* __restrict__ dinv,
                                                    int* __restrict__ counts,
                                                    ushort4* __restrict__ base4, int n) {
    int i = blockIdx.x * 256 + threadIdx.x;
    if (i > n) return;
    if (i == n) { counts[n] = 0; return; }
    uint4 p = packed4[i];
    unsigned c0 = p.x >> 20, c1 = p.y >> 20, c2 = p.z >> 20, c3 = p.w >> 20;
    unsigned wfix = (p.x & 0xFFFFFu) + (p.y & 0xFFFFFu) + (p.z & 0xFFFFFu) + (p.w & 0xFFFFFu);
    counts[i] = (int)(c0 + c1 + c2 + c3);
    float deg = (float)wfix * (1.0f / 16384.0f);
    dinv[i] = rsqrtf(deg + 1.0f);
    base4[i] = make_ushort4(0, (unsigned short)c0, (unsigned short)(c0 + c1),
                            (unsigned short)(c0 + c1 + c2));
}

// ---------------- hierarchical exclusive scan over m = n+1 elements ----------------
__global__ __launch_bounds__(256) void scan1_kernel(const int* __restrict__ counts,
                                                    int* __restrict__ rowptr,
                                                    int* __restrict__ bsum, int m) {
    __shared__ int wtot[4];
    int base = blockIdx.x * 1024 + (int)threadIdx.x * 4;
    int v0 = 0, v1 = 0, v2 = 0, v3 = 0;
    if (base + 3 < m) {
        int4 c = *reinterpret_cast<const int4*>(counts + base);
        v0 = c.x; v1 = c.y; v2 = c.z; v3 = c.w;
    } else {
        if (base + 0 < m) v0 = counts[base + 0];
        if (base + 1 < m) v1 = counts[base + 1];
        if (base + 2 < m) v2 = counts[base + 2];
        if (base + 3 < m) v3 = counts[base + 3];
    }
    int t = v0 + v1 + v2 + v3;
    int lane = threadIdx.x & 63, wid = threadIdx.x >> 6;
    int incl = t;
#pragma unroll
    for (int off = 1; off < 64; off <<= 1) {
        int u = __shfl_up(incl, off, 64);
        if (lane >= off) incl += u;
    }
    if (lane == 63) wtot[wid] = incl;
    __syncthreads();
    int woff = 0;
#pragma unroll
    for (int w = 0; w < 4; ++w) if (w < wid) woff += wtot[w];
    int ex = woff + incl - t;
    if (base < m) {
        int e0 = ex, e1 = ex + v0, e2 = ex + v0 + v1, e3 = ex + v0 + v1 + v2;
        if (base + 3 < m) {
            *reinterpret_cast<int4*>(rowptr + base) = make_int4(e0, e1, e2, e3);
        } else {
            rowptr[base] = e0;
            if (base + 1 < m) rowptr[base + 1] = e1;
            if (base + 2 < m) rowptr[base + 2] = e2;
        }
    }
    if (threadIdx.x == 255) bsum[blockIdx.x] = woff + incl;
}

__global__ __launch_bounds__(64) void scan2_kernel(int* __restrict__ bsum, int nb) {
    int lane = threadIdx.x;
    int carry = 0;
    for (int base = 0; base < nb; base += 64) {
        int i = base + lane;
        int v = (i < nb) ? bsum[i] : 0;
        int incl = v;
#pragma unroll
        for (int off = 1; off < 64; off <<= 1) {
            int u = __shfl_up(incl, off, 64);
            if (lane >= off) incl += u;
        }
        if (i < nb) bsum[i] = carry + incl - v;
        carry += __shfl(incl, 63, 64);
    }
}

__global__ __launch_bounds__(256) void scan3_kernel(int* __restrict__ rowptr,
                                                    const int* __restrict__ bsum, int m) {
    int i = blockIdx.x * 256 + threadIdx.x;
    if (i < m) rowptr[i] += bsum[i >> 10];
}

// ---------------- pass B: atomic-free CSR scatter ----------------
__global__ __launch_bounds__(256) void build_kernel(const int* __restrict__ src,
                                                    const int* __restrict__ dst,
                                                    const float* __restrict__ ew,
                                                    const float* __restrict__ dinv,
                                                    const int* __restrict__ rowptr,
                                                    const ushort4* __restrict__ base4,
                                                    const unsigned short* __restrict__ rank,
                                                    int2* __restrict__ csr, int E) {
    int e = blockIdx.x * 256 + threadIdx.x;
    if (e >= E) return;
    int d = dst[e], s = src[e];
    ushort4 b4 = base4[d];
    int r = e & 3;
    int rb = (r == 0) ? b4.x : (r == 1) ? b4.y : (r == 2) ? b4.z : b4.w;
    int pos = rowptr[d] + rb + (int)rank[e];
    float w = ew[e] * dinv[s];
    csr[pos] = make_int2(s, __float_as_int(w));
}

// ---------------- gather-aggregate (F=64): one wave per dst row ----------------
// Lane l: eg = l>>4 (edge subgroup), fq = l&15 (feature float4).
// out[row] = (BIAS? b : 0) + dinv*( dinv*H[row] + sum_j w_j*H[src_j] )
template<bool BIAS>
__global__ __launch_bounds__(256) void gagg64_kernel(const int* __restrict__ rowptr,
                                                     const int2* __restrict__ csr,
                                                     const float* __restrict__ dinv,
                                                     const float* __restrict__ H,
                                                     const float* __restrict__ b,
                                                     float* __restrict__ out, int n) {
    int row  = (blockIdx.x * 256 + threadIdx.x) >> 6;
    int lane = threadIdx.x & 63;
    if (row >= n) return;
    int eg = lane >> 4, fq = lane & 15;
    int beg = rowptr[row], end = rowptr[row + 1];
    float dv = dinv[row];
    const float4* H4 = reinterpret_cast<const float4*>(H);

    float ax = 0.f, ay = 0.f, az = 0.f, aw = 0.f;
    int j = beg;
    for (; j + 16 <= end; j += 16) {
        int2 m0 = csr[j + eg];
        int2 m1 = csr[j + eg + 4];
        int2 m2 = csr[j + eg + 8];
        int2 m3 = csr[j + eg + 12];
        float4 h0 = H4[(size_t)m0.x * 16 + fq];
        float4 h1 = H4[(size_t)m1.x * 16 + fq];
        float4 h2 = H4[(size_t)m2.x * 16 + fq];
        float4 h3 = H4[(size_t)m3.x * 16 + fq];
        float w0 = __int_as_float(m0.y), w1 = __int_as_float(m1.y);
        float w2 = __int_as_float(m2.y), w3 = __int_as_float(m3.y);
        ax += w0 * h0.x; ay += w0 * h0.y; az += w0 * h0.z; aw += w0 * h0.w;
        ax += w1 * h1.x; ay += w1 * h1.y; az += w1 * h1.z; aw += w1 * h1.w;
        ax += w2 * h2.x; ay += w2 * h2.y; az += w2 * h2.z; aw += w2 * h2.w;
        ax += w3 * h3.x; ay += w3 * h3.y; az += w3 * h3.z; aw += w3 * h3.w;
    }
    for (; j + 4 <= end; j += 4) {
        int2 m0 = csr[j + eg];
        float w0 = __int_as_float(m0.y);
        float4 h0 = H4[(size_t)m0.x * 16 + fq];
        ax += w0 * h0.x; ay += w0 * h0.y; az += w0 * h0.z; aw += w0 * h0.w;
    }
    if (j < end) {
        int idx = j + eg;
        if (idx < end) {
            int2 m0 = csr[idx];
            float w0 = __int_as_float(m0.y);
            float4 h0 = H4[(size_t)m0.x * 16 + fq];
            ax += w0 * h0.x; ay += w0 * h0.y; az += w0 * h0.z; aw += w0 * h0.w;
        }
    }
    // combine the 4 edge subgroups (lanes differing in bits 4,5)
    ax += __shfl_xor(ax, 16, 64); ay += __shfl_xor(ay, 16, 64);
    az += __shfl_xor(az, 16, 64); aw += __shfl_xor(aw, 16, 64);
    ax += __shfl_xor(ax, 32, 64); ay += __shfl_xor(ay, 32, 64);
    az += __shfl_xor(az, 32, 64); aw += __shfl_xor(aw, 32, 64);

    if (eg == 0) {
        float4 self = H4[(size_t)row * 16 + fq];
        float4 o;
        o.x = dv * (ax + dv * self.x);
        o.y = dv * (ay + dv * self.y);
        o.z = dv * (az + dv * self.z);
        o.w = dv * (aw + dv * self.w);
        if (BIAS) {
            float4 bb = ld4(b + fq * 4);
            o.x += bb.x; o.y += bb.y; o.z += bb.z; o.w += bb.w;
        }
        reinterpret_cast<float4*>(out)[(size_t)row * 16 + fq] = o;
    }
}

// ---------------- dense matmul: Y = (X @ W) [+b] [relu] ----------------
template<int FIN, int FOUT, bool RELU, bool BIAS>
__global__ __launch_bounds__(256) void matmulE_kernel(const float* __restrict__ X,
                                                      const float* __restrict__ W,
                                                      const float* __restrict__ b,
                                                      float* __restrict__ Y, int n) {
    constexpr int QPR = FOUT / 4;     // threads per row (4 outputs each)
    constexpr int RPB = 256 / QPR;    // rows per block
    __shared__ float Ws[FIN * FOUT];  // 32 KiB
    for (int i = threadIdx.x; i < FIN * FOUT / 4; i += 256)
        reinterpret_cast<float4*>(Ws)[i] = reinterpret_cast<const float4*>(W)[i];
    __syncthreads();

    int r = blockIdx.x * RPB + threadIdx.x / QPR;
    int q = threadIdx.x % QPR;
    if (r >= n) return;
    const float* xr = X + (size_t)r * FIN;

    float ax = 0.f, ay = 0.f, az = 0.f, aw = 0.f;
#pragma unroll
    for (int k = 0; k < FIN; k += 4) {
        float4 a = ld4(xr + k);
        float4 w0 = ld4(&Ws[(k + 0) * FOUT + q * 4]);
        float4 w1 = ld4(&Ws[(k + 1) * FOUT + q * 4]);
        float4 w2 = ld4(&Ws[(k + 2) * FOUT + q * 4]);
        float4 w3 = ld4(&Ws[(k + 3) * FOUT + q * 4]);
        ax += a.x * w0.x + a.y * w1.x + a.z * w2.x + a.w * w3.x;
        ay += a.x * w0.y + a.y * w1.y + a.z * w2.y + a.w * w3.y;
        az += a.x * w0.z + a.y * w1.z + a.z * w2.z + a.w * w3.z;
        aw += a.x * w0.w + a.y * w1.w + a.z * w2.w + a.w * w3.w;
    }
    float4 o = make_float4(ax, ay, az, aw);
    if (BIAS) {
        float4 bb = ld4(b + q * 4);
        o.x += bb.x; o.y += bb.y; o.z += bb.z; o.w += bb.w;
    }
    if (RELU) {
        o.x = fmaxf(o.x, 0.f); o.y = fmaxf(o.y, 0.f);
        o.z = fmaxf(o.z, 0.f); o.w = fmaxf(o.w, 0.f);
    }
    *reinterpret_cast<float4*>(Y + (size_t)r * FOUT + q * 4) = o;
}

extern "C" void kernel_launch(void* const* d_in, const int* in_sizes, int n_in,
                              void* d_out, int out_size, void* d_ws, size_t ws_size,
                              hipStream_t stream) {
    const float* z  = (const float*)d_in[0];
    const int*   ei = (const int*)d_in[1];
    const float* ea = (const float*)d_in[2];
    const float* W1 = (const float*)d_in[3];
    const float* b1 = (const float*)d_in[4];
    const float* W2 = (const float*)d_in[5];
    const float* b2 = (const float*)d_in[6];
    float* out = (float*)d_out;

    const int n = in_sizes[0] / 64;   // LAT = 64
    const int E = in_sizes[2];
    const int* src = ei;
    const int* dst = ei + E;
    const int m  = n + 1;             // scan length
    const int nb = (m + 1023) / 1024; // scan blocks

    float* ws = (float*)d_ws;
    size_t p = 0;
    auto alloc = [&](size_t elems) { size_t o = p; p += (elems + 63) & ~63ull; return o; };
    float*          dinv    = ws + alloc(n);
    unsigned int*   packed4 = (unsigned int*)(ws + alloc((size_t)n * 4));
    ushort4*        base4   = (ushort4*)(ws + alloc((size_t)n * 2));
    int*            counts  = (int*)(ws + alloc(m));
    int*            rowptr  = (int*)(ws + alloc(m));
    int*            bsum    = (int*)(ws + alloc(4096));
    unsigned short* rank    = (unsigned short*)(ws + alloc(((size_t)E + 1) / 2));
    int2*           csr     = (int2*)(ws + alloc((size_t)E * 2));
    float*          t1      = ws + alloc((size_t)n * 64);   // Â z, later hh = h@W2
    float*          h       = ws + alloc((size_t)n * 128);  // relu(t1@W1+b1)
    (void)ws_size;

    // ---- graph preprocessing (shared by both layers) ----
    hipMemsetAsync(packed4, 0, (size_t)n * 4 * sizeof(unsigned int), stream);
    degpack_kernel<<<(E + 1023) / 1024, 256, 0, stream>>>(dst, ea, packed4, rank, E);
    merge_kernel<<<(m + 255) / 256, 256, 0, stream>>>((const uint4*)packed4, dinv,
                                                      counts, base4, n);
    scan1_kernel<<<nb, 256, 0, stream>>>(counts, rowptr, bsum, m);
    scan2_kernel<<<1, 64, 0, stream>>>(bsum, nb);
    scan3_kernel<<<(m + 255) / 256, 256, 0, stream>>>(rowptr, bsum, m);
    build_kernel<<<(E + 255) / 256, 256, 0, stream>>>(src, dst, ea, dinv,
                                                      rowptr, base4, rank, csr, E);

    // ---- layer 1: t1 = Â z ; h = relu(t1 @ W1 + b1) ----
    gagg64_kernel<false><<<(n + 3) / 4, 256, 0, stream>>>(rowptr, csr, dinv,
                                                          z, nullptr, t1, n);
    matmulE_kernel<64, 128, true, true><<<(n + 7) / 8, 256, 0, stream>>>(t1, W1, b1, h, n);

    // ---- layer 2: hh = h @ W2 ; out = Â hh + b2 ----   (hh reuses t1)
    matmulE_kernel<128, 64, false, false><<<(n + 15) / 16, 256, 0, stream>>>(h, W2, nullptr, t1, n);
    gagg64_kernel<true><<<(n + 3) / 4, 256, 0, stream>>>(rowptr, csr, dinv,
                                                         t1, b2, out, n);
}

// Round 6
// 213.513 us; speedup vs baseline: 1.2380x; 1.2380x over previous
//
#include <hip/hip_runtime.h>

// 2-layer GCN, CSR-gather formulation, v6.
//   Â = D^{-1/2}(A+I)D^{-1/2},  out = Â(relu(Â z W1 + b1))W2 + b2
// layer1: t1 = Â z (64-wide), h = relu(t1@W1+b1); layer2: hh = h@W2, out = Â hh + b2.
// v6: CSR build via two-level LDS counting sort by dst — ZERO global atomics
// (R2-R5 established a ~22-25 Gops/s scattered-global-atomic ceiling; degpack's
// 1.6M atomics cost 65us no matter how spread). Degrees fall out of the sort.

#define NPB 128   // nodes per fine bucket (dst & 127 is the in-bucket id)
#define CH  4096  // edges per chunk block in hist/scatter passes

__device__ __forceinline__ float4 ld4(const float* p) {
    return *reinterpret_cast<const float4*>(p);
}

// ---- K1: coarse histogram per chunk (LDS), bucket-major out: hist[b*G1+g] ----
__global__ __launch_bounds__(256) void hist_kernel(const int* __restrict__ dst,
                                                   int* __restrict__ hist,
                                                   int E, int G1, int NBKT) {
    __shared__ int lh[512];
    for (int i = threadIdx.x; i < NBKT; i += 256) lh[i] = 0;
    __syncthreads();
    int g = blockIdx.x;
    int beg = g * CH, end = min(beg + CH, E);
    for (int j = beg + (int)threadIdx.x; j < end; j += 256)
        atomicAdd(&lh[dst[j] / NPB], 1);
    __syncthreads();
    for (int i = threadIdx.x; i < NBKT; i += 256) hist[(size_t)i * G1 + g] = lh[i];
}

// ---- K2a: per-bucket exclusive scan across chunks (in place); btot[b] = total ----
__global__ __launch_bounds__(64) void bscan_kernel(int* __restrict__ hist,
                                                   int* __restrict__ btot, int G1) {
    int b = blockIdx.x;
    int* row = hist + (size_t)b * G1;
    int lane = threadIdx.x;
    int carry = 0;
    for (int g0 = 0; g0 < G1; g0 += 64) {
        int g = g0 + lane;
        int v = (g < G1) ? row[g] : 0;
        int incl = v;
#pragma unroll
        for (int off = 1; off < 64; off <<= 1) {
            int u = __shfl_up(incl, off, 64);
            if (lane >= off) incl += u;
        }
        if (g < G1) row[g] = carry + incl - v;
        carry += __shfl(incl, 63, 64);
    }
    if (lane == 0) btot[b] = carry;
}

// ---- K2b: exclusive scan of bucket totals -> bucket bases (NBKT <= 512) ----
__global__ __launch_bounds__(512) void tscan_kernel(const int* __restrict__ btot,
                                                    int* __restrict__ bbase, int NBKT) {
    __shared__ int ws[8];
    int t = threadIdx.x;
    int v = (t < NBKT) ? btot[t] : 0;
    int lane = t & 63, wid = t >> 6;
    int incl = v;
#pragma unroll
    for (int off = 1; off < 64; off <<= 1) {
        int u = __shfl_up(incl, off, 64);
        if (lane >= off) incl += u;
    }
    if (lane == 63) ws[wid] = incl;
    __syncthreads();
    int woff = 0;
#pragma unroll
    for (int w = 0; w < 8; ++w) if (w < wid) woff += ws[w];
    if (t < NBKT) bbase[t] = woff + incl - v;
}

// ---- K3: scatter edges into bucket-grouped tmp via LDS cursors ----
// tmp[pos] = { (dst&127)<<24 | src , ew }   (src < 2^24)
__global__ __launch_bounds__(256) void scatter_kernel(const int* __restrict__ src,
                                                      const int* __restrict__ dst,
                                                      const float* __restrict__ ew,
                                                      const int* __restrict__ hist,
                                                      const int* __restrict__ bbase,
                                                      int2* __restrict__ tmp,
                                                      int E, int G1, int NBKT) {
    __shared__ int cursor[512];
    int g = blockIdx.x;
    for (int i = threadIdx.x; i < NBKT; i += 256)
        cursor[i] = bbase[i] + hist[(size_t)i * G1 + g];
    __syncthreads();
    int beg = g * CH, end = min(beg + CH, E);
    for (int j = beg + (int)threadIdx.x; j < end; j += 256) {
        int d = dst[j];
        int b = d / NPB;
        int pos = atomicAdd(&cursor[b], 1);
        tmp[pos] = make_int2(((d & (NPB - 1)) << 24) | src[j], __float_as_int(ew[j]));
    }
}

// ---- K4: per-bucket finalize: exact rowptr, dinv, final CSR {src, ew} ----
// LDS hist[dlow]: bits 24..31 count, bits 0..23 sum(ew) in 2^-14 fixed point.
__global__ __launch_bounds__(256) void finalize_kernel(const int2* __restrict__ tmp,
                                                       const int* __restrict__ bbase,
                                                       const int* __restrict__ btot,
                                                       int* __restrict__ rowptr,
                                                       float* __restrict__ dinv,
                                                       int2* __restrict__ csr,
                                                       int n, int E) {
    __shared__ unsigned int hist[NPB];
    __shared__ int wsum_[2];
    int b = blockIdx.x;
    int base = bbase[b];
    int cnt  = btot[b];
    int tid  = threadIdx.x;
    if (tid < NPB) hist[tid] = 0;
    __syncthreads();
    // phase A: packed count + weighted degree
    for (int j = tid; j < cnt; j += 256) {
        int2 t = tmp[base + j];
        unsigned dlow = ((unsigned)t.x) >> 24;
        unsigned wfix = (unsigned)(__int_as_float(t.y) * 16384.0f);
        atomicAdd(&hist[dlow], (1u << 24) | wfix);
    }
    __syncthreads();
    int c = 0, incl = 0;
    unsigned pk = 0;
    if (tid < NPB) {
        pk = hist[tid];
        c = (int)(pk >> 24);
        incl = c;
#pragma unroll
        for (int off = 1; off < 64; off <<= 1) {
            int u = __shfl_up(incl, off, 64);
            if ((tid & 63) >= off) incl += u;
        }
        if ((tid & 63) == 63) wsum_[tid >> 6] = incl;
    }
    __syncthreads();
    if (tid < NPB) {
        int woff = (tid >= 64) ? wsum_[0] : 0;
        int excl = woff + incl - c;
        int node = b * NPB + tid;
        if (node < n) {
            rowptr[node] = base + excl;
            float wdeg = (float)(pk & 0xFFFFFFu) * (1.0f / 16384.0f);
            dinv[node] = rsqrtf(wdeg + 1.0f);
        }
        hist[tid] = (unsigned)excl;   // becomes cursor for phase B
    }
    if (b == 0 && tid == 0) rowptr[n] = E;
    __syncthreads();
    // phase B: place edges within bucket
    for (int j = tid; j < cnt; j += 256) {
        int2 t = tmp[base + j];
        unsigned dlow = ((unsigned)t.x) >> 24;
        int srcv = t.x & 0xFFFFFF;
        int lr = (int)atomicAdd(&hist[dlow], 1u);
        csr[base + lr] = make_int2(srcv, t.y);
    }
}

// ---- K5: csr.w *= dinv[src]  (dinv is small & cache-resident) ----
__global__ __launch_bounds__(256) void wscale_kernel(int2* __restrict__ csr,
                                                     const float* __restrict__ dinv,
                                                     int E) {
    int base = blockIdx.x * 1024 + (int)threadIdx.x;
#pragma unroll
    for (int k = 0; k < 4; ++k) {
        int e = base + k * 256;
        if (e < E) {
            int2 c = csr[e];
            float w = __int_as_float(c.y) * dinv[c.x];
            csr[e] = make_int2(c.x, __float_as_int(w));
        }
    }
}

// ---- gather-aggregate (F=64): one wave per dst row, 16 edges in flight ----
// Lane l: eg = l>>4 (edge subgroup), fq = l&15 (feature float4).
template<bool BIAS>
__global__ __launch_bounds__(256) void gagg64_kernel(const int* __restrict__ rowptr,
                                                     const int2* __restrict__ csr,
                                                     const float* __restrict__ dinv,
                                                     const float* __restrict__ H,
                                                     const float* __restrict__ b,
                                                     float* __restrict__ out, int n) {
    int row  = (blockIdx.x * 256 + threadIdx.x) >> 6;
    int lane = threadIdx.x & 63;
    if (row >= n) return;
    int eg = lane >> 4, fq = lane & 15;
    int beg = rowptr[row], end = rowptr[row + 1];
    float dv = dinv[row];
    const float4* H4 = reinterpret_cast<const float4*>(H);

    float ax = 0.f, ay = 0.f, az = 0.f, aw = 0.f;
    int j = beg;
    for (; j + 16 <= end; j += 16) {
        int2 m0 = csr[j + eg];
        int2 m1 = csr[j + eg + 4];
        int2 m2 = csr[j + eg + 8];
        int2 m3 = csr[j + eg + 12];
        float4 h0 = H4[(size_t)m0.x * 16 + fq];
        float4 h1 = H4[(size_t)m1.x * 16 + fq];
        float4 h2 = H4[(size_t)m2.x * 16 + fq];
        float4 h3 = H4[(size_t)m3.x * 16 + fq];
        float w0 = __int_as_float(m0.y), w1 = __int_as_float(m1.y);
        float w2 = __int_as_float(m2.y), w3 = __int_as_float(m3.y);
        ax += w0 * h0.x; ay += w0 * h0.y; az += w0 * h0.z; aw += w0 * h0.w;
        ax += w1 * h1.x; ay += w1 * h1.y; az += w1 * h1.z; aw += w1 * h1.w;
        ax += w2 * h2.x; ay += w2 * h2.y; az += w2 * h2.z; aw += w2 * h2.w;
        ax += w3 * h3.x; ay += w3 * h3.y; az += w3 * h3.z; aw += w3 * h3.w;
    }
    for (; j + 4 <= end; j += 4) {
        int2 m0 = csr[j + eg];
        float w0 = __int_as_float(m0.y);
        float4 h0 = H4[(size_t)m0.x * 16 + fq];
        ax += w0 * h0.x; ay += w0 * h0.y; az += w0 * h0.z; aw += w0 * h0.w;
    }
    if (j < end) {
        int idx = j + eg;
        if (idx < end) {
            int2 m0 = csr[idx];
            float w0 = __int_as_float(m0.y);
            float4 h0 = H4[(size_t)m0.x * 16 + fq];
            ax += w0 * h0.x; ay += w0 * h0.y; az += w0 * h0.z; aw += w0 * h0.w;
        }
    }
    ax += __shfl_xor(ax, 16, 64); ay += __shfl_xor(ay, 16, 64);
    az += __shfl_xor(az, 16, 64); aw += __shfl_xor(aw, 16, 64);
    ax += __shfl_xor(ax, 32, 64); ay += __shfl_xor(ay, 32, 64);
    az += __shfl_xor(az, 32, 64); aw += __shfl_xor(aw, 32, 64);

    if (eg == 0) {
        float4 self = H4[(size_t)row * 16 + fq];
        float4 o;
        o.x = dv * (ax + dv * self.x);
        o.y = dv * (ay + dv * self.y);
        o.z = dv * (az + dv * self.z);
        o.w = dv * (aw + dv * self.w);
        if (BIAS) {
            float4 bb = ld4(b + fq * 4);
            o.x += bb.x; o.y += bb.y; o.z += bb.z; o.w += bb.w;
        }
        reinterpret_cast<float4*>(out)[(size_t)row * 16 + fq] = o;
    }
}

// ---- dense matmul: Y = (X @ W) [+b] [relu] ----
template<int FIN, int FOUT, bool RELU, bool BIAS>
__global__ __launch_bounds__(256) void matmulE_kernel(const float* __restrict__ X,
                                                      const float* __restrict__ W,
                                                      const float* __restrict__ b,
                                                      float* __restrict__ Y, int n) {
    constexpr int QPR = FOUT / 4;
    constexpr int RPB = 256 / QPR;
    __shared__ float Ws[FIN * FOUT];
    for (int i = threadIdx.x; i < FIN * FOUT / 4; i += 256)
        reinterpret_cast<float4*>(Ws)[i] = reinterpret_cast<const float4*>(W)[i];
    __syncthreads();

    int r = blockIdx.x * RPB + threadIdx.x / QPR;
    int q = threadIdx.x % QPR;
    if (r >= n) return;
    const float* xr = X + (size_t)r * FIN;

    float ax = 0.f, ay = 0.f, az = 0.f, aw = 0.f;
#pragma unroll
    for (int k = 0; k < FIN; k += 4) {
        float4 a = ld4(xr + k);
        float4 w0 = ld4(&Ws[(k + 0) * FOUT + q * 4]);
        float4 w1 = ld4(&Ws[(k + 1) * FOUT + q * 4]);
        float4 w2 = ld4(&Ws[(k + 2) * FOUT + q * 4]);
        float4 w3 = ld4(&Ws[(k + 3) * FOUT + q * 4]);
        ax += a.x * w0.x + a.y * w1.x + a.z * w2.x + a.w * w3.x;
        ay += a.x * w0.y + a.y * w1.y + a.z * w2.y + a.w * w3.y;
        az += a.x * w0.z + a.y * w1.z + a.z * w2.z + a.w * w3.z;
        aw += a.x * w0.w + a.y * w1.w + a.z * w2.w + a.w * w3.w;
    }
    float4 o = make_float4(ax, ay, az, aw);
    if (BIAS) {
        float4 bb = ld4(b + q * 4);
        o.x += bb.x; o.y += bb.y; o.z += bb.z; o.w += bb.w;
    }
    if (RELU) {
        o.x = fmaxf(o.x, 0.f); o.y = fmaxf(o.y, 0.f);
        o.z = fmaxf(o.z, 0.f); o.w = fmaxf(o.w, 0.f);
    }
    *reinterpret_cast<float4*>(Y + (size_t)r * FOUT + q * 4) = o;
}

extern "C" void kernel_launch(void* const* d_in, const int* in_sizes, int n_in,
                              void* d_out, int out_size, void* d_ws, size_t ws_size,
                              hipStream_t stream) {
    const float* z  = (const float*)d_in[0];
    const int*   ei = (const int*)d_in[1];
    const float* ea = (const float*)d_in[2];
    const float* W1 = (const float*)d_in[3];
    const float* b1 = (const float*)d_in[4];
    const float* W2 = (const float*)d_in[5];
    const float* b2 = (const float*)d_in[6];
    float* out = (float*)d_out;

    const int n = in_sizes[0] / 64;   // LAT = 64
    const int E = in_sizes[2];
    const int* src = ei;
    const int* dst = ei + E;
    const int NBKT = (n + NPB - 1) / NPB;   // 391 for n=50000 (<=512 required)
    const int G1   = (E + CH - 1) / CH;     // chunk blocks

    float* ws = (float*)d_ws;
    size_t p = 0;
    auto alloc = [&](size_t elems) { size_t o = p; p += (elems + 63) & ~63ull; return o; };
    float* dinv   = ws + alloc(n);
    int*   rowptr = (int*)(ws + alloc((size_t)n + 1));
    int*   btot   = (int*)(ws + alloc(NBKT));
    int*   bbase  = (int*)(ws + alloc(NBKT));
    int2*  csr    = (int2*)(ws + alloc((size_t)E * 2));
    float* t1     = ws + alloc((size_t)n * 64);    // Â z, later hh = h@W2
    // region X: tmp+hist (preprocessing) then h (layers) — tmp dead before h written
    float* X      = ws + alloc((size_t)n * 128);
    int2*  tmp    = (int2*)X;                       // E int2
    int*   hist   = (int*)(X + (size_t)E * 2);      // NBKT*G1 ints
    float* h      = X;
    (void)ws_size;

    // ---- preprocessing: counting sort by dst, zero global atomics ----
    hist_kernel<<<G1, 256, 0, stream>>>(dst, hist, E, G1, NBKT);
    bscan_kernel<<<NBKT, 64, 0, stream>>>(hist, btot, G1);
    tscan_kernel<<<1, 512, 0, stream>>>(btot, bbase, NBKT);
    scatter_kernel<<<G1, 256, 0, stream>>>(src, dst, ea, hist, bbase, tmp, E, G1, NBKT);
    finalize_kernel<<<NBKT, 256, 0, stream>>>(tmp, bbase, btot, rowptr, dinv, csr, n, E);
    wscale_kernel<<<(E + 1023) / 1024, 256, 0, stream>>>(csr, dinv, E);

    // ---- layer 1: t1 = Â z ; h = relu(t1 @ W1 + b1) ----
    gagg64_kernel<false><<<(n + 3) / 4, 256, 0, stream>>>(rowptr, csr, dinv,
                                                          z, nullptr, t1, n);
    matmulE_kernel<64, 128, true, true><<<(n + 7) / 8, 256, 0, stream>>>(t1, W1, b1, h, n);

    // ---- layer 2: hh = h @ W2 ; out = Â hh + b2 ----   (hh reuses t1)
    matmulE_kernel<128, 64, false, false><<<(n + 15) / 16, 256, 0, stream>>>(h, W2, nullptr, t1, n);
    gagg64_kernel<true><<<(n + 3) / 4, 256, 0, stream>>>(rowptr, csr, dinv,
                                                         t1, b2, out, n);
}

// Round 7
// 189.479 us; speedup vs baseline: 1.3950x; 1.1268x over previous
//
#include <hip/hip_runtime.h>

// 2-layer GCN, CSR-gather formulation, v7.
//   Â = D^{-1/2}(A+I)D^{-1/2},  out = Â(relu(Â z W1 + b1))W2 + b2
// layer1: t1 = Â z (64-wide), h = relu(t1@W1+b1); layer2: hh = h@W2, out = Â hh + b2.
// v6: CSR build via two-level LDS counting sort by dst — zero global atomics.
// v7: gather operands stored as bf16 (z->zb copy; hh written bf16 by matmul2):
// halves the gagg fetch bytes (R6 showed gagg plateaued at ~3.4 TB/s fetch
// service; bytes are the lever, not MLP). Accumulation/CSR/outputs stay f32.

#define NPB 128   // nodes per fine bucket (dst & 127 is the in-bucket id)
#define CH  4096  // edges per chunk block in hist/scatter passes

__device__ __forceinline__ float4 ld4(const float* p) {
    return *reinterpret_cast<const float4*>(p);
}

// round-to-nearest-even f32 -> bf16 (as ushort in low bits)
__device__ __forceinline__ unsigned bfr(float f) {
    unsigned u = __float_as_uint(f);
    return (u + 0x7FFFu + ((u >> 16) & 1u)) >> 16;
}
// unpack 4 bf16 (uint2) -> 4 f32
__device__ __forceinline__ void bf4(uint2 v, float& f0, float& f1, float& f2, float& f3) {
    f0 = __uint_as_float(v.x << 16);
    f1 = __uint_as_float(v.x & 0xFFFF0000u);
    f2 = __uint_as_float(v.y << 16);
    f3 = __uint_as_float(v.y & 0xFFFF0000u);
}

// ---- K1: coarse histogram per chunk (LDS), bucket-major out: hist[b*G1+g] ----
__global__ __launch_bounds__(256) void hist_kernel(const int* __restrict__ dst,
                                                   int* __restrict__ hist,
                                                   int E, int G1, int NBKT) {
    __shared__ int lh[512];
    for (int i = threadIdx.x; i < NBKT; i += 256) lh[i] = 0;
    __syncthreads();
    int g = blockIdx.x;
    int beg = g * CH, end = min(beg + CH, E);
    for (int j = beg + (int)threadIdx.x; j < end; j += 256)
        atomicAdd(&lh[dst[j] / NPB], 1);
    __syncthreads();
    for (int i = threadIdx.x; i < NBKT; i += 256) hist[(size_t)i * G1 + g] = lh[i];
}

// ---- K2a: per-bucket exclusive scan across chunks (in place); btot[b] = total ----
__global__ __launch_bounds__(64) void bscan_kernel(int* __restrict__ hist,
                                                   int* __restrict__ btot, int G1) {
    int b = blockIdx.x;
    int* row = hist + (size_t)b * G1;
    int lane = threadIdx.x;
    int carry = 0;
    for (int g0 = 0; g0 < G1; g0 += 64) {
        int g = g0 + lane;
        int v = (g < G1) ? row[g] : 0;
        int incl = v;
#pragma unroll
        for (int off = 1; off < 64; off <<= 1) {
            int u = __shfl_up(incl, off, 64);
            if (lane >= off) incl += u;
        }
        if (g < G1) row[g] = carry + incl - v;
        carry += __shfl(incl, 63, 64);
    }
    if (lane == 0) btot[b] = carry;
}

// ---- K2b: exclusive scan of bucket totals -> bucket bases (NBKT <= 512) ----
__global__ __launch_bounds__(512) void tscan_kernel(const int* __restrict__ btot,
                                                    int* __restrict__ bbase, int NBKT) {
    __shared__ int ws[8];
    int t = threadIdx.x;
    int v = (t < NBKT) ? btot[t] : 0;
    int lane = t & 63, wid = t >> 6;
    int incl = v;
#pragma unroll
    for (int off = 1; off < 64; off <<= 1) {
        int u = __shfl_up(incl, off, 64);
        if (lane >= off) incl += u;
    }
    if (lane == 63) ws[wid] = incl;
    __syncthreads();
    int woff = 0;
#pragma unroll
    for (int w = 0; w < 8; ++w) if (w < wid) woff += ws[w];
    if (t < NBKT) bbase[t] = woff + incl - v;
}

// ---- K3: scatter edges into bucket-grouped tmp via LDS cursors ----
__global__ __launch_bounds__(256) void scatter_kernel(const int* __restrict__ src,
                                                      const int* __restrict__ dst,
                                                      const float* __restrict__ ew,
                                                      const int* __restrict__ hist,
                                                      const int* __restrict__ bbase,
                                                      int2* __restrict__ tmp,
                                                      int E, int G1, int NBKT) {
    __shared__ int cursor[512];
    int g = blockIdx.x;
    for (int i = threadIdx.x; i < NBKT; i += 256)
        cursor[i] = bbase[i] + hist[(size_t)i * G1 + g];
    __syncthreads();
    int beg = g * CH, end = min(beg + CH, E);
    for (int j = beg + (int)threadIdx.x; j < end; j += 256) {
        int d = dst[j];
        int b = d / NPB;
        int pos = atomicAdd(&cursor[b], 1);
        tmp[pos] = make_int2(((d & (NPB - 1)) << 24) | src[j], __float_as_int(ew[j]));
    }
}

// ---- K4: per-bucket finalize: exact rowptr, dinv, final CSR {src, ew} ----
__global__ __launch_bounds__(256) void finalize_kernel(const int2* __restrict__ tmp,
                                                       const int* __restrict__ bbase,
                                                       const int* __restrict__ btot,
                                                       int* __restrict__ rowptr,
                                                       float* __restrict__ dinv,
                                                       int2* __restrict__ csr,
                                                       int n, int E) {
    __shared__ unsigned int hist[NPB];
    __shared__ int wsum_[2];
    int b = blockIdx.x;
    int base = bbase[b];
    int cnt  = btot[b];
    int tid  = threadIdx.x;
    if (tid < NPB) hist[tid] = 0;
    __syncthreads();
    for (int j = tid; j < cnt; j += 256) {
        int2 t = tmp[base + j];
        unsigned dlow = ((unsigned)t.x) >> 24;
        unsigned wfix = (unsigned)(__int_as_float(t.y) * 16384.0f);
        atomicAdd(&hist[dlow], (1u << 24) | wfix);
    }
    __syncthreads();
    int c = 0, incl = 0;
    unsigned pk = 0;
    if (tid < NPB) {
        pk = hist[tid];
        c = (int)(pk >> 24);
        incl = c;
#pragma unroll
        for (int off = 1; off < 64; off <<= 1) {
            int u = __shfl_up(incl, off, 64);
            if ((tid & 63) >= off) incl += u;
        }
        if ((tid & 63) == 63) wsum_[tid >> 6] = incl;
    }
    __syncthreads();
    if (tid < NPB) {
        int woff = (tid >= 64) ? wsum_[0] : 0;
        int excl = woff + incl - c;
        int node = b * NPB + tid;
        if (node < n) {
            rowptr[node] = base + excl;
            float wdeg = (float)(pk & 0xFFFFFFu) * (1.0f / 16384.0f);
            dinv[node] = rsqrtf(wdeg + 1.0f);
        }
        hist[tid] = (unsigned)excl;
    }
    if (b == 0 && tid == 0) rowptr[n] = E;
    __syncthreads();
    for (int j = tid; j < cnt; j += 256) {
        int2 t = tmp[base + j];
        unsigned dlow = ((unsigned)t.x) >> 24;
        int srcv = t.x & 0xFFFFFF;
        int lr = (int)atomicAdd(&hist[dlow], 1u);
        csr[base + lr] = make_int2(srcv, t.y);
    }
}

// ---- K5: csr.w *= dinv[src]  (dinv is small & cache-resident) ----
__global__ __launch_bounds__(256) void wscale_kernel(int2* __restrict__ csr,
                                                     const float* __restrict__ dinv,
                                                     int E) {
    int base = blockIdx.x * 1024 + (int)threadIdx.x;
#pragma unroll
    for (int k = 0; k < 4; ++k) {
        int e = base + k * 256;
        if (e < E) {
            int2 c = csr[e];
            float w = __int_as_float(c.y) * dinv[c.x];
            csr[e] = make_int2(c.x, __float_as_int(w));
        }
    }
}

// ---- K6: f32 -> packed bf16 conversion (m = number of uint outputs) ----
__global__ __launch_bounds__(256) void convb_kernel(const float* __restrict__ in,
                                                    unsigned* __restrict__ out, int m) {
    int i = blockIdx.x * 256 + threadIdx.x;
    if (i < m) {
        float2 f = reinterpret_cast<const float2*>(in)[i];
        out[i] = bfr(f.x) | (bfr(f.y) << 16);
    }
}

// ---- gather-aggregate (F=64, bf16 operand): one wave per dst row ----
// Lane l: eg = l>>4 (edge subgroup), fq = l&15 (feature uint2 = 4 bf16).
// out[row] = (BIAS? b : 0) + dinv*( dinv*H[row] + sum_j w_j*H[src_j] )   (f32 out)
template<bool BIAS>
__global__ __launch_bounds__(256) void gaggb_kernel(const int* __restrict__ rowptr,
                                                    const int2* __restrict__ csr,
                                                    const float* __restrict__ dinv,
                                                    const uint2* __restrict__ Hb,
                                                    const float* __restrict__ b,
                                                    float* __restrict__ out, int n) {
    int row  = (blockIdx.x * 256 + threadIdx.x) >> 6;
    int lane = threadIdx.x & 63;
    if (row >= n) return;
    int eg = lane >> 4, fq = lane & 15;
    int beg = rowptr[row], end = rowptr[row + 1];
    float dv = dinv[row];

    float ax = 0.f, ay = 0.f, az = 0.f, aw = 0.f;
    int j = beg;
    for (; j + 16 <= end; j += 16) {
        int2 m0 = csr[j + eg];
        int2 m1 = csr[j + eg + 4];
        int2 m2 = csr[j + eg + 8];
        int2 m3 = csr[j + eg + 12];
        uint2 v0 = Hb[(size_t)m0.x * 16 + fq];
        uint2 v1 = Hb[(size_t)m1.x * 16 + fq];
        uint2 v2 = Hb[(size_t)m2.x * 16 + fq];
        uint2 v3 = Hb[(size_t)m3.x * 16 + fq];
        float w0 = __int_as_float(m0.y), w1 = __int_as_float(m1.y);
        float w2 = __int_as_float(m2.y), w3 = __int_as_float(m3.y);
        float f0, f1, f2, f3;
        bf4(v0, f0, f1, f2, f3);
        ax += w0 * f0; ay += w0 * f1; az += w0 * f2; aw += w0 * f3;
        bf4(v1, f0, f1, f2, f3);
        ax += w1 * f0; ay += w1 * f1; az += w1 * f2; aw += w1 * f3;
        bf4(v2, f0, f1, f2, f3);
        ax += w2 * f0; ay += w2 * f1; az += w2 * f2; aw += w2 * f3;
        bf4(v3, f0, f1, f2, f3);
        ax += w3 * f0; ay += w3 * f1; az += w3 * f2; aw += w3 * f3;
    }
    for (; j + 4 <= end; j += 4) {
        int2 m0 = csr[j + eg];
        float w0 = __int_as_float(m0.y);
        uint2 v0 = Hb[(size_t)m0.x * 16 + fq];
        float f0, f1, f2, f3;
        bf4(v0, f0, f1, f2, f3);
        ax += w0 * f0; ay += w0 * f1; az += w0 * f2; aw += w0 * f3;
    }
    if (j < end) {
        int idx = j + eg;
        if (idx < end) {
            int2 m0 = csr[idx];
            float w0 = __int_as_float(m0.y);
            uint2 v0 = Hb[(size_t)m0.x * 16 + fq];
            float f0, f1, f2, f3;
            bf4(v0, f0, f1, f2, f3);
            ax += w0 * f0; ay += w0 * f1; az += w0 * f2; aw += w0 * f3;
        }
    }
    ax += __shfl_xor(ax, 16, 64); ay += __shfl_xor(ay, 16, 64);
    az += __shfl_xor(az, 16, 64); aw += __shfl_xor(aw, 16, 64);
    ax += __shfl_xor(ax, 32, 64); ay += __shfl_xor(ay, 32, 64);
    az += __shfl_xor(az, 32, 64); aw += __shfl_xor(aw, 32, 64);

    if (eg == 0) {
        uint2 sv = Hb[(size_t)row * 16 + fq];
        float s0, s1, s2, s3;
        bf4(sv, s0, s1, s2, s3);
        float4 o;
        o.x = dv * (ax + dv * s0);
        o.y = dv * (ay + dv * s1);
        o.z = dv * (az + dv * s2);
        o.w = dv * (aw + dv * s3);
        if (BIAS) {
            float4 bb = ld4(b + fq * 4);
            o.x += bb.x; o.y += bb.y; o.z += bb.z; o.w += bb.w;
        }
        reinterpret_cast<float4*>(out)[(size_t)row * 16 + fq] = o;
    }
}

// ---- dense matmul: Y = (X @ W) [+b] [relu]; optional bf16-packed output ----
template<int FIN, int FOUT, bool RELU, bool BIAS, bool OUTB>
__global__ __launch_bounds__(256) void matmulE_kernel(const float* __restrict__ X,
                                                      const float* __restrict__ W,
                                                      const float* __restrict__ b,
                                                      void* __restrict__ Y, int n) {
    constexpr int QPR = FOUT / 4;
    constexpr int RPB = 256 / QPR;
    __shared__ float Ws[FIN * FOUT];
    for (int i = threadIdx.x; i < FIN * FOUT / 4; i += 256)
        reinterpret_cast<float4*>(Ws)[i] = reinterpret_cast<const float4*>(W)[i];
    __syncthreads();

    int r = blockIdx.x * RPB + threadIdx.x / QPR;
    int q = threadIdx.x % QPR;
    if (r >= n) return;
    const float* xr = X + (size_t)r * FIN;

    float ax = 0.f, ay = 0.f, az = 0.f, aw = 0.f;
#pragma unroll
    for (int k = 0; k < FIN; k += 4) {
        float4 a = ld4(xr + k);
        float4 w0 = ld4(&Ws[(k + 0) * FOUT + q * 4]);
        float4 w1 = ld4(&Ws[(k + 1) * FOUT + q * 4]);
        float4 w2 = ld4(&Ws[(k + 2) * FOUT + q * 4]);
        float4 w3 = ld4(&Ws[(k + 3) * FOUT + q * 4]);
        ax += a.x * w0.x + a.y * w1.x + a.z * w2.x + a.w * w3.x;
        ay += a.x * w0.y + a.y * w1.y + a.z * w2.y + a.w * w3.y;
        az += a.x * w0.z + a.y * w1.z + a.z * w2.z + a.w * w3.z;
        aw += a.x * w0.w + a.y * w1.w + a.z * w2.w + a.w * w3.w;
    }
    float4 o = make_float4(ax, ay, az, aw);
    if (BIAS) {
        float4 bb = ld4(b + q * 4);
        o.x += bb.x; o.y += bb.y; o.z += bb.z; o.w += bb.w;
    }
    if (RELU) {
        o.x = fmaxf(o.x, 0.f); o.y = fmaxf(o.y, 0.f);
        o.z = fmaxf(o.z, 0.f); o.w = fmaxf(o.w, 0.f);
    }
    if (OUTB) {
        uint2 pv = make_uint2(bfr(o.x) | (bfr(o.y) << 16),
                              bfr(o.z) | (bfr(o.w) << 16));
        reinterpret_cast<uint2*>(Y)[(size_t)r * QPR + q] = pv;
    } else {
        reinterpret_cast<float4*>(Y)[(size_t)r * QPR + q] = o;
    }
}

extern "C" void kernel_launch(void* const* d_in, const int* in_sizes, int n_in,
                              void* d_out, int out_size, void* d_ws, size_t ws_size,
                              hipStream_t stream) {
    const float* z  = (const float*)d_in[0];
    const int*   ei = (const int*)d_in[1];
    const float* ea = (const float*)d_in[2];
    const float* W1 = (const float*)d_in[3];
    const float* b1 = (const float*)d_in[4];
    const float* W2 = (const float*)d_in[5];
    const float* b2 = (const float*)d_in[6];
    float* out = (float*)d_out;

    const int n = in_sizes[0] / 64;   // LAT = 64
    const int E = in_sizes[2];
    const int* src = ei;
    const int* dst = ei + E;
    const int NBKT = (n + NPB - 1) / NPB;   // 391 for n=50000 (<=512 required)
    const int G1   = (E + CH - 1) / CH;     // chunk blocks

    float* ws = (float*)d_ws;
    size_t p = 0;
    auto alloc = [&](size_t elems) { size_t o = p; p += (elems + 63) & ~63ull; return o; };
    float* dinv   = ws + alloc(n);
    int*   rowptr = (int*)(ws + alloc((size_t)n + 1));
    int*   btot   = (int*)(ws + alloc(NBKT));
    int*   bbase  = (int*)(ws + alloc(NBKT));
    int2*  csr    = (int2*)(ws + alloc((size_t)E * 2));
    float* t1     = ws + alloc((size_t)n * 64);    // Â z (f32), later h input
    unsigned* zb  = (unsigned*)(ws + alloc((size_t)n * 32));  // bf16 z; later bf16 hh
    // region X: tmp+hist (preprocessing) then h (layers) — tmp dead before h written
    float* X      = ws + alloc((size_t)n * 128);
    int2*  tmp    = (int2*)X;                       // E int2
    int*   hist   = (int*)(X + (size_t)E * 2);      // NBKT*G1 ints
    float* h      = X;
    (void)ws_size;

    // ---- preprocessing: counting sort by dst, zero global atomics ----
    hist_kernel<<<G1, 256, 0, stream>>>(dst, hist, E, G1, NBKT);
    bscan_kernel<<<NBKT, 64, 0, stream>>>(hist, btot, G1);
    tscan_kernel<<<1, 512, 0, stream>>>(btot, bbase, NBKT);
    scatter_kernel<<<G1, 256, 0, stream>>>(src, dst, ea, hist, bbase, tmp, E, G1, NBKT);
    finalize_kernel<<<NBKT, 256, 0, stream>>>(tmp, bbase, btot, rowptr, dinv, csr, n, E);
    wscale_kernel<<<(E + 1023) / 1024, 256, 0, stream>>>(csr, dinv, E);
    convb_kernel<<<(n * 32 + 255) / 256, 256, 0, stream>>>(z, zb, n * 32);

    // ---- layer 1: t1 = Â z ; h = relu(t1 @ W1 + b1) ----
    gaggb_kernel<false><<<(n + 3) / 4, 256, 0, stream>>>(rowptr, csr, dinv,
                                                         (const uint2*)zb, nullptr, t1, n);
    matmulE_kernel<64, 128, true, true, false><<<(n + 7) / 8, 256, 0, stream>>>(
        t1, W1, b1, h, n);

    // ---- layer 2: hh = bf16(h @ W2) (reuses zb) ; out = Â hh + b2 ----
    matmulE_kernel<128, 64, false, false, true><<<(n + 15) / 16, 256, 0, stream>>>(
        h, W2, nullptr, zb, n);
    gaggb_kernel<true><<<(n + 3) / 4, 256, 0, stream>>>(rowptr, csr, dinv,
                                                        (const uint2*)zb, b2, out, n);
}